// Round 6
// baseline (112.117 us; speedup 1.0000x reference)
//
#include <hip/hip_runtime.h>
#include <hip/hip_bf16.h>

typedef __hip_bfloat16 bf16;
typedef __attribute__((ext_vector_type(8))) short short8v;   // bf16x8 MFMA fragment
typedef __attribute__((ext_vector_type(4))) float f32x4;     // MFMA accumulator

#define NB   32
#define NTT  512
#define NJ   17
#define ND   128
#define NP   6
#define NH   4
#define NDH  32
#define NBT  (NB*NTT)        // 16384 frames
#define NG   4               // frames per block
#define NTOK (NG*NP)         // 24 tokens per block
#define NMT  2               // M-tiles (24 rows -> 2x16, 8 pad rows)
#define NTHR 512             // 8 waves
#define TSTR 136             // bf16 row stride: 272B -> 4-bank row step, 2-way (free)
#define YSTR 132             // y fp32 row stride: 528B, 16B-aligned

// ws layout: bf16 wgt[81920]: [0,16384) Wp | [16384,65536) Wc=Win*Wp | [65536,81920) Wo
// then fp32 bc[384] at byte offset 163840.
#define WS_WP 0
#define WS_WC 16384
#define WS_WO 65536

// LDS arena offsets (bytes)
#define OFF_POOL 0            // [24][136] bf16 = 6528
#define OFF_TOKP 6528         // [24][136] bf16
#define OFF_Q    13056        // [24][136] bf16 ; o overwrites q after PV
#define OFF_K    19584        // [24][136] bf16 ; dead after scores
#define OFF_V    26112        // [24][136] bf16 ; dead after PV
#define OFF_Y    19584        // [24][132] fp32 = 12672 aliases k|v (ends 32256)
#define OFF_PROB 32640        // [4*4*6*6] fp32 = 2304
#define OFF_MU   34944        // [24] fp32
#define OFF_INV  35040        // [24] fp32
#define ARENA_SZ 35136

__device__ __forceinline__ float bf2f(unsigned short u) {
    return __uint_as_float(((unsigned)u) << 16);
}
__device__ __forceinline__ f32x4 MFMA(short8v a, short8v b, f32x4 c) {
    return __builtin_amdgcn_mfma_f32_16x16x32_bf16(a, b, c, 0, 0, 0);
}
// B-fragment from bf16 weight (row-major [dout][k] == B^T): one 16B load.
__device__ __forceinline__ short8v ldB(const bf16* __restrict__ W, int nt, int ks, int lane) {
    return *reinterpret_cast<const short8v*>(W + (nt*16 + (lane & 15))*ND + ks*32 + ((lane >> 4) << 3));
}
// A-fragment from bf16 LDS tile (row stride TSTR). Pad rows clamp in-bounds.
__device__ __forceinline__ short8v ldsA(const bf16* __restrict__ s, int mt, int ks, int lane) {
    int row = mt*16 + (lane & 15);
    if (row >= NTOK) row = NTOK - 1;
    return *reinterpret_cast<const short8v*>(s + row*TSTR + ks*32 + ((lane >> 4) << 3));
}

// ---- K0: fp32 -> bf16 conversion of Wp, Wo ----
extern "C" __global__ __launch_bounds__(256)
void wconv(const float* __restrict__ Wp, const float* __restrict__ Wo,
           bf16* __restrict__ ws) {
    int i = blockIdx.x*256 + threadIdx.x;     // 32768 total
    if (i < 16384) ws[WS_WP + i] = __float2bfloat16(Wp[i]);
    else           ws[WS_WO + (i - 16384)] = __float2bfloat16(Wo[i - 16384]);
}

// ---- K1: Wc = Win @ Wp (384x128), bc = Win @ bp + bin ----
extern "C" __global__ __launch_bounds__(128)
void wcomb(const float* __restrict__ Wp, const float* __restrict__ Wi,
           const float* __restrict__ bp, const float* __restrict__ bi,
           bf16* __restrict__ wc, float* __restrict__ bc) {
    __shared__ float s_red[128];
    const int n = blockIdx.x;          // 0..383
    const int k = threadIdx.x;         // 0..127
    float acc = 0.f;
    #pragma unroll 4
    for (int m = 0; m < 128; ++m)
        acc = fmaf(Wi[n*128+m], Wp[m*128+k], acc);   // Wi read scalar, Wp coalesced
    wc[n*128+k] = __float2bfloat16(acc);
    s_red[k] = Wi[n*128+k]*bp[k];
    __syncthreads();
    #pragma unroll
    for (int s = 64; s > 0; s >>= 1) {
        if (k < s) s_red[k] += s_red[k+s];
        __syncthreads();
    }
    if (k == 0) bc[n] = s_red[0] + bi[n];
}

extern "C" __global__ __launch_bounds__(NTHR, 8)
void bpa_fused(const float* __restrict__ h_joint,
               const float* __restrict__ mask_joint,
               const bf16* __restrict__ wgt, const float* __restrict__ bc,
               const float* __restrict__ b_proj, const float* __restrict__ b_out,
               const float* __restrict__ ln_g,  const float* __restrict__ ln_b,
               float* __restrict__ out)
{
    __shared__ __align__(16) unsigned char s_arena[ARENA_SZ];
    bf16*  s_pool  = reinterpret_cast<bf16*>(s_arena + OFF_POOL);
    bf16*  s_tokp  = reinterpret_cast<bf16*>(s_arena + OFF_TOKP);
    bf16*  s_q     = reinterpret_cast<bf16*>(s_arena + OFF_Q);
    bf16*  s_k     = reinterpret_cast<bf16*>(s_arena + OFF_K);
    bf16*  s_v     = reinterpret_cast<bf16*>(s_arena + OFF_V);
    float* s_y     = reinterpret_cast<float*>(s_arena + OFF_Y);
    float* s_probs = reinterpret_cast<float*>(s_arena + OFF_PROB);
    float* s_mu    = reinterpret_cast<float*>(s_arena + OFF_MU);
    float* s_inv   = reinterpret_cast<float*>(s_arena + OFF_INV);

    const int tid  = threadIdx.x;
    const int lane = tid & 63;
    const int w    = tid >> 6;                          // wave 0..7
    const long frame0 = (long)blockIdx.x * NG;

    // Prefetch W_proj B-fragments (tile w) — overlaps with pooling loads.
    short8v bwp[4];
    #pragma unroll
    for (int ks = 0; ks < 4; ++ks) bwp[ks] = ldB(wgt + WS_WP, w, ks, lane);

    // ---- Stage 1: pooling, unconditional & independent loads ----
    {
        const int f = tid >> 7;
        const int d = tid & (ND-1);
        const float* hcol = h_joint + (frame0 + f)*(long)(NJ*ND) + d;
        const float* mrow = mask_joint + (frame0 + f)*(long)NJ;

        float hv[NJ];
        #pragma unroll
        for (int j = 0; j < NJ; ++j) hv[j] = hcol[j*ND];      // independent
        unsigned mb = 0;
        #pragma unroll
        for (int j = 0; j < NJ; ++j)
            mb |= (mrow[j] > 0.05f) ? (1u << j) : 0u;          // independent
        #pragma unroll
        for (int j = 0; j < NJ; ++j)
            hv[j] = (mb >> j & 1) ? hv[j] : 0.f;

        float acc[NP];
        acc[0] = ((hv[0]+hv[1]) + (hv[2]+hv[3])) + hv[4];
        acc[1] = (hv[5]+hv[6]) + (hv[11]+hv[12]);
        acc[2] = hv[5]+hv[7]+hv[9];
        acc[3] = hv[6]+hv[8]+hv[10];
        acc[4] = hv[11]+hv[13]+hv[15];
        acc[5] = hv[12]+hv[14]+hv[16];
        const unsigned pm[NP] = {0x1Fu, 0x1860u, 0x2A0u, 0x540u, 0xA800u, 0x15000u};
        #pragma unroll
        for (int p = 0; p < NP; ++p) {
            float cnt = (float)__popc(mb & pm[p]);
            s_pool[(f*NP+p)*TSTR + d] = __float2bfloat16(acc[p] / fmaxf(cnt, 1e-6f));
        }
    }
    __syncthreads();

    // ---- Stage 2: tok = pool@Wp^T + bp  AND  qkv = pool@Wc^T + bc (one phase) ----
    {
        // tok tile (N-tile w of Wp)
        f32x4 acc[NMT];
        acc[0] = (f32x4)(0.f); acc[1] = (f32x4)(0.f);
        #pragma unroll
        for (int ks = 0; ks < 4; ++ks)
            #pragma unroll
            for (int mt = 0; mt < NMT; ++mt)
                acc[mt] = MFMA(ldsA(s_pool, mt, ks, lane), bwp[ks], acc[mt]);
        int col = w*16 + (lane & 15);
        float bv = b_proj[col];
        #pragma unroll
        for (int mt = 0; mt < NMT; ++mt)
            #pragma unroll
            for (int j = 0; j < 4; ++j) {
                int row = mt*16 + ((lane >> 4) << 2) + j;
                if (row < NTOK)
                    s_tokp[row*TSTR + col] = __float2bfloat16(acc[mt][j] + bv);
            }
    }
    #pragma unroll
    for (int t = 0; t < 3; ++t) {           // q, k, v tiles from combined Wc
        int nt = t*8 + w;
        short8v bw[4];
        #pragma unroll
        for (int ks = 0; ks < 4; ++ks) bw[ks] = ldB(wgt + WS_WC, nt, ks, lane);
        f32x4 acc[NMT];
        acc[0] = (f32x4)(0.f); acc[1] = (f32x4)(0.f);
        #pragma unroll
        for (int ks = 0; ks < 4; ++ks)
            #pragma unroll
            for (int mt = 0; mt < NMT; ++mt)
                acc[mt] = MFMA(ldsA(s_pool, mt, ks, lane), bw[ks], acc[mt]);
        bf16* dst = (t == 0) ? s_q : (t == 1) ? s_k : s_v;
        int lcol = w*16 + (lane & 15);
        float bv = bc[nt*16 + (lane & 15)];
        #pragma unroll
        for (int mt = 0; mt < NMT; ++mt)
            #pragma unroll
            for (int j = 0; j < 4; ++j) {
                int row = mt*16 + ((lane >> 4) << 2) + j;
                if (row < NTOK)
                    dst[row*TSTR + lcol] = __float2bfloat16(acc[mt][j] + bv);
            }
    }
    __syncthreads();

    // ---- Stage 3: attention scores + softmax -> s_probs ----
    if (tid < NG*NH*NP) {   // 96 threads: (f, h, qi)
        int f   = tid / (NH*NP);
        int rem = tid - f*(NH*NP);
        int h   = rem / NP;
        int qi  = rem - h*NP;
        const bf16* qrow = s_q + (f*NP+qi)*TSTR + h*NDH;
        float sc[NP];
        float mx = -1e30f;
        #pragma unroll
        for (int pk = 0; pk < NP; ++pk) {
            const bf16* krow = s_k + (f*NP+pk)*TSTR + h*NDH;
            float s = 0.f;
            #pragma unroll
            for (int c = 0; c < NDH; c += 4) {
                ushort4 uq = *reinterpret_cast<const ushort4*>(qrow + c);
                ushort4 uk = *reinterpret_cast<const ushort4*>(krow + c);
                s += bf2f(uq.x)*bf2f(uk.x) + bf2f(uq.y)*bf2f(uk.y)
                   + bf2f(uq.z)*bf2f(uk.z) + bf2f(uq.w)*bf2f(uk.w);
            }
            sc[pk] = s * 0.17677669529663688f;   // 1/sqrt(32)
            mx = fmaxf(mx, sc[pk]);
        }
        float den = 0.f, e[NP];
        #pragma unroll
        for (int pk = 0; pk < NP; ++pk) { e[pk] = expf(sc[pk]-mx); den += e[pk]; }
        float inv = 1.f/den;
        #pragma unroll
        for (int pk = 0; pk < NP; ++pk)
            s_probs[((f*NH+h)*NP+qi)*NP + pk] = e[pk]*inv;
    }
    __syncthreads();

    // ---- Stage 4: part_importance + o = w @ v (o overwrites q region) ----
    if (tid < NG*NP) {  // 24 threads: (f, pk)
        int f = tid / NP, pk = tid - f*NP;
        float s = 0.f;
        #pragma unroll
        for (int h = 0; h < NH; ++h)
            #pragma unroll
            for (int q = 0; q < NP; ++q)
                s += s_probs[((f*NH+h)*NP+q)*NP + pk];
        out[(long)NBT*NP*ND + (frame0+f)*NP + pk] = s * (1.f/24.f);
    }
    #pragma unroll
    for (int i = 0; i < (NTOK*ND)/NTHR; ++i) {   // 6 iters
        int idx = i*NTHR + tid;
        int token = idx >> 7;
        int d = idx & (ND-1);
        int f = token / NP, qi = token - f*NP;
        int h = d >> 5;
        const float* pr = s_probs + ((f*NH+h)*NP+qi)*NP;
        float s = 0.f;
        #pragma unroll
        for (int pk = 0; pk < NP; ++pk) {
            float v = bf2f(reinterpret_cast<const unsigned short*>(s_v)[(f*NP+pk)*TSTR + d]);
            s += pr[pk]*v;
        }
        s_q[token*TSTR + d] = __float2bfloat16(s);   // o over dead q
    }
    __syncthreads();

    // ---- Stage 5: y = o @ Wo^T + b_out + tok -> fp32 y over dead k|v ----
    {
        short8v bo[4];
        #pragma unroll
        for (int ks = 0; ks < 4; ++ks) bo[ks] = ldB(wgt + WS_WO, w, ks, lane);
        f32x4 acc[NMT];
        acc[0] = (f32x4)(0.f); acc[1] = (f32x4)(0.f);
        #pragma unroll
        for (int ks = 0; ks < 4; ++ks)
            #pragma unroll
            for (int mt = 0; mt < NMT; ++mt)
                acc[mt] = MFMA(ldsA(s_q, mt, ks, lane), bo[ks], acc[mt]);
        int col = w*16 + (lane & 15);
        float bv = b_out[col];
        #pragma unroll
        for (int mt = 0; mt < NMT; ++mt)
            #pragma unroll
            for (int j = 0; j < 4; ++j) {
                int row = mt*16 + ((lane >> 4) << 2) + j;
                if (row < NTOK) {
                    float resid = bf2f(*reinterpret_cast<const unsigned short*>(&s_tokp[row*TSTR + col]));
                    s_y[row*YSTR + col] = acc[mt][j] + bv + resid;
                }
            }
    }
    __syncthreads();

    // ---- Stage 6: LayerNorm stats (4 lanes per token) ----
    if (tid < NTOK*4) {   // 96 threads
        int token = tid >> 2, sub = tid & 3;
        const float* row = s_y + token*YSTR + sub*NDH;
        float s = 0.f, s2 = 0.f;
        #pragma unroll
        for (int j = 0; j < NDH; j += 4) {
            float4 v = *reinterpret_cast<const float4*>(row + j);
            s  += v.x + v.y + v.z + v.w;
            s2 += v.x*v.x + v.y*v.y + v.z*v.z + v.w*v.w;
        }
        s  += __shfl_xor(s, 1);  s  += __shfl_xor(s, 2);
        s2 += __shfl_xor(s2, 1); s2 += __shfl_xor(s2, 2);
        float mean = s * (1.f/128.f);
        float var  = s2 * (1.f/128.f) - mean*mean;
        if (sub == 0) {
            s_mu[token]  = mean;
            s_inv[token] = rsqrtf(var + 1e-5f);
        }
    }
    __syncthreads();

    // ---- Stage 7: normalize + coalesced store (768 float4, 512 threads) ----
    #pragma unroll
    for (int i = 0; i < 2; ++i) {
        int idx4 = i*NTHR + tid;
        if (idx4 < NTOK*(ND/4)) {
            int token = idx4 >> 5;
            int dj = (idx4 & 31) << 2;
            float mean = s_mu[token], inv = s_inv[token];
            float4 v = *reinterpret_cast<const float4*>(s_y + token*YSTR + dj);
            float4 g = *reinterpret_cast<const float4*>(ln_g + dj);
            float4 b = *reinterpret_cast<const float4*>(ln_b + dj);
            float4 r;
            r.x = (v.x-mean)*inv*g.x + b.x;
            r.y = (v.y-mean)*inv*g.y + b.y;
            r.z = (v.z-mean)*inv*g.z + b.z;
            r.w = (v.w-mean)*inv*g.w + b.w;
            *reinterpret_cast<float4*>(out + (frame0*NP + token)*(long)ND + dj) = r;
        }
    }
}

extern "C" void kernel_launch(void* const* d_in, const int* in_sizes, int n_in,
                              void* d_out, int out_size, void* d_ws, size_t ws_size,
                              hipStream_t stream) {
    const float* h_joint = (const float*)d_in[0];
    const float* mask    = (const float*)d_in[1];
    const float* W_proj  = (const float*)d_in[2];
    const float* b_proj  = (const float*)d_in[3];
    const float* W_in    = (const float*)d_in[4];
    const float* b_in    = (const float*)d_in[5];
    const float* W_out   = (const float*)d_in[6];
    const float* b_out   = (const float*)d_in[7];
    const float* ln_g    = (const float*)d_in[8];
    const float* ln_b    = (const float*)d_in[9];
    float* out = (float*)d_out;
    bf16*  wgt = (bf16*)d_ws;                              // 81920 bf16 = 163840 B
    float* bc  = (float*)((char*)d_ws + 163840);           // 384 fp32

    hipLaunchKernelGGL(wconv, dim3(32768/256), dim3(256), 0, stream,
                       W_proj, W_out, wgt);
    hipLaunchKernelGGL(wcomb, dim3(384), dim3(128), 0, stream,
                       W_proj, W_in, b_proj, b_in, wgt + WS_WC, bc);
    hipLaunchKernelGGL(bpa_fused, dim3(NBT/NG), dim3(NTHR), 0, stream,
                       h_joint, mask, wgt, bc, b_proj, b_out, ln_g, ln_b, out);
}